// Round 6
// baseline (130.070 us; speedup 1.0000x reference)
//
#include <hip/hip_runtime.h>
#include <math.h>

#define B_   4
#define L_   32768
#define DI   20
#define NS   10
#define TBLK 128          // timesteps per chunk/block
#define NCB  256          // chunks per batch

// fp32 offsets in ws (floats)
#define OFF_AP   0u
#define OFF_RS   204800u
#define OFF_SC   409600u
#define OFF_H16  430192u   // h16 region (16B aligned)
// half offsets within h16 region
#define HD  0u             // delta [80][32768]
#define HU  2621440u       // u
#define HB  5242880u       // B [40][32768]
#define HC  6553600u       // C

typedef _Float16 h16;
typedef _Float16 half8 __attribute__((ext_vector_type(8)));
typedef _Float16 half4 __attribute__((ext_vector_type(4)));
typedef float f32x4 __attribute__((ext_vector_type(4)));

// ---- DPP helpers: row_shr within 16-lane rows, OOB lanes -> identity ----
template<int CTRL>
__device__ __forceinline__ float dppf(float idv, float src) {
    union U { float f; int i; };
    U o, s, r; o.f = idv; s.f = src;
    r.i = __builtin_amdgcn_update_dpp(o.i, s.i, CTRL, 0xf, 0xf, false);
    return r.f;
}
#define ROW_SHR1 0x111
#define ROW_SHR2 0x112
#define ROW_SHR4 0x114
#define ROW_SHR8 0x118

#define OPSCAN16(Ac, Bc) \
    { float aP = dppf<ROW_SHR1>(1.0f, Ac); float bP = dppf<ROW_SHR1>(0.0f, Bc); \
      Bc = fmaf(Ac, bP, Bc); Ac *= aP; \
      aP = dppf<ROW_SHR2>(1.0f, Ac); bP = dppf<ROW_SHR2>(0.0f, Bc); \
      Bc = fmaf(Ac, bP, Bc); Ac *= aP; \
      aP = dppf<ROW_SHR4>(1.0f, Ac); bP = dppf<ROW_SHR4>(0.0f, Bc); \
      Bc = fmaf(Ac, bP, Bc); Ac *= aP; \
      aP = dppf<ROW_SHR8>(1.0f, Ac); bP = dppf<ROW_SHR8>(0.0f, Bc); \
      Bc = fmaf(Ac, bP, Bc); Ac *= aP; }

#define SUMSCAN16(v) \
    { v += dppf<ROW_SHR1>(0.0f, v); v += dppf<ROW_SHR2>(0.0f, v); \
      v += dppf<ROW_SHR4>(0.0f, v); v += dppf<ROW_SHR8>(0.0f, v); }

// ---- k1 LDS layout (halves) ----
#define XS_   0
#define MT_   2640
#define UL_   0
#define DS__  0
#define DUS_  2720
#define XP5_  4608
#define BS_   5448
#define WXo   6808
#define WDTo  7808
#define BDTo  7908
#define BXo   7928
#define POOLH 7956
#define WF_   7956         // halves offset of 1600-float scratch (phase A only)
#define POOL2 (POOLH + 3200)

// =============== k1: weight preformat + MFMA front-end + chunk scan ======
// Also writes the DEFAULT output y = u*D for its whole chunk (t-thread owns
// the 20 contiguous floats of out[b, l0+t, :]), so kD only fixes up active
// chunks.
__global__ __launch_bounds__(320) void k1(
    const float* __restrict__ x,
    const float* __restrict__ w_in, const float* __restrict__ b_in,
    const float* __restrict__ conv_k, const float* __restrict__ conv_b,
    const float* __restrict__ w_x, const float* __restrict__ b_x,
    const float* __restrict__ w_dt, const float* __restrict__ b_dt,
    const float* __restrict__ A_log, const float* __restrict__ D_param,
    h16* __restrict__ dh, h16* __restrict__ uh,
    h16* __restrict__ Bh, h16* __restrict__ Ch,
    float* __restrict__ ap_ws, float* __restrict__ rs_ws, float* __restrict__ sc_ws,
    float* __restrict__ out)
{
    __shared__ __align__(16) h16 P[POOL2];
    __shared__ float beff_s[20];
    __shared__ float ALs[200];     // -exp(A_log)
    __shared__ float D_s[20];

    const int tid = threadIdx.x;
    const int c   = blockIdx.x;
    const int b   = blockIdx.y;
    const int l0  = c * TBLK;

    // ---------- Phase A1: raw weights -> LDS float scratch ----------
    {
        float* Wf = (float*)&P[WF_];   // 1600 floats: w_in 20x20 @0, conv_k @400
        for (int i = tid; i < 400;  i += 320) Wf[i]       = w_in[(i/20)*40 + (i%20)];
        for (int i = tid; i < 1200; i += 320) Wf[400 + i] = conv_k[i];
        for (int i = tid; i < 200;  i += 320) ALs[i] = -__expf(A_log[i]);
        if (tid < 20) D_s[tid] = D_param[tid];
    }
    __syncthreads();

    // ---------- Phase A2: preformat weights (h16) + beff + stage x ----------
    {
        const float* Wf = (const float*)&P[WF_];
        for (int e = tid; e < 1200; e += 320) {        // MeffT [20][72]
            int cc = e/20, o = e - cc*20;
            int w = cc/20, i = cc - w*20;
            float acc = 0.0f;
            #pragma unroll
            for (int op = 0; op < 20; op++)
                acc = fmaf(Wf[i*20 + op], Wf[400 + (w*20 + op)*20 + o], acc);
            P[MT_ + o*72 + cc] = (h16)acc;
        }
        for (int i = tid; i < 240; i += 320) {          // zero MT cols 60..71
            int o = i/12, cc = 60 + (i - (i/12)*12);
            P[MT_ + o*72 + cc] = (h16)0.0f;
        }
        for (int i = tid; i < 1000; i += 320) {         // WxT[j][k=d]
            int j = i/40, k = i - j*40;
            P[WXo + i] = (k < 20) ? (h16)w_x[k*25 + j] : (h16)0.0f;
        }
        for (int i = tid; i < 100; i += 320) P[WDTo + i] = (h16)w_dt[i];
        if (tid < 20) P[BDTo + tid] = (h16)b_dt[tid];
        if (tid < 25) P[BXo + tid] = (h16)b_x[tid];
        if (tid < 20) {
            float be = conv_b[tid];
            #pragma unroll
            for (int w = 0; w < 3; w++)
                #pragma unroll
                for (int op = 0; op < 20; op++)
                    be = fmaf(b_in[op], Wf[400 + (w*20 + op)*20 + tid], be);
            beff_s[tid] = be;
        }
        // x window -> XS (does not overlap MT_/WF_)
        const float* xb = x + ((size_t)b*L_ + l0)*DI - 2*DI;
        for (int i = tid; i < 1320; i += 320) {
            float2 v;
            if (i >= 1300 || (c == 0 && i < 20)) v = make_float2(0.0f, 0.0f);
            else v = *(const float2*)(xb + 2*i);
            P[XS_ + 2*i]     = (h16)v.x;
            P[XS_ + 2*i + 1] = (h16)v.y;
        }
    }
    __syncthreads();   // b1

    // ---------- P2: u_pre = Xflat @ Meff (MFMA), +beff, silu ----------
    const int wv  = tid >> 6;
    const int ln  = tid & 63;
    const int m16 = ln & 15;
    const int q   = ln >> 4;
    float uval[4][4];
    if (wv < 4) {
        #pragma unroll
        for (int jj = 0; jj < 4; jj++) {
            int job = wv*4 + jj, mt = job >> 1, nt = job & 1;
            int t_row = mt*16 + m16;
            int dcol  = nt*16 + m16;
            int dmin  = dcol < 20 ? dcol : 19;
            f32x4 acc = {0.0f, 0.0f, 0.0f, 0.0f};
            #pragma unroll
            for (int kh = 0; kh < 2; kh++) {
                half8 af, bf;
                int ab = XS_ + t_row*20 + kh*32 + (q<<3);
                *(half4*)&af         = *(const half4*)&P[ab];
                *(((half4*)&af) + 1) = *(const half4*)&P[ab + 4];
                int bb = MT_ + dmin*72 + kh*32 + (q<<3);
                *(half4*)&bf         = *(const half4*)&P[bb];
                *(((half4*)&bf) + 1) = *(const half4*)&P[bb + 4];
                acc = __builtin_amdgcn_mfma_f32_16x16x32_f16(af, bf, acc, 0, 0, 0);
            }
            float bfv = beff_s[dmin];
            #pragma unroll
            for (int r = 0; r < 4; r++) {
                float a = acc[r] + bfv;
                uval[jj][r] = a * __builtin_amdgcn_rcpf(1.0f + __expf(-a));
            }
        }
    }
    __syncthreads();   // b2: XS dead -> UL may overwrite

    if (wv < 4) {
        #pragma unroll
        for (int jj = 0; jj < 4; jj++) {
            int job = wv*4 + jj, mt = job >> 1, nt = job & 1;
            int dcol = nt*16 + m16;
            if (dcol < 20) {
                #pragma unroll
                for (int r = 0; r < 4; r++)
                    P[UL_ + (mt*16 + q*4 + r)*36 + dcol] = (h16)uval[jj][r];
            }
        }
    }
    // NOTE: UL cols 20..31 stay stale (finite h16 from prior phases) — WxT
    // rows k>=20 are zero, so the P3 MFMA contribution of those k is 0.
    __syncthreads();   // b3

    // ---------- P3: xp = u @ w_x (MFMA), +b_x; stash XP5/BS; Ch direct ----------
    float xv[4][4];
    if (wv < 4) {
        #pragma unroll
        for (int jj = 0; jj < 4; jj++) {
            int job = wv*4 + jj, mt = job >> 1, nt = job & 1;
            int t_row = mt*16 + m16;
            int j     = nt*16 + m16;
            int jmin  = j < 25 ? j : 24;
            f32x4 acc = {0.0f, 0.0f, 0.0f, 0.0f};
            half8 af, bf;
            int ab = UL_ + t_row*36 + (q<<3);
            *(half4*)&af         = *(const half4*)&P[ab];
            *(((half4*)&af) + 1) = *(const half4*)&P[ab + 4];
            int bb = WXo + jmin*40 + (q<<3);
            *(half4*)&bf         = *(const half4*)&P[bb];
            *(((half4*)&bf) + 1) = *(const half4*)&P[bb + 4];
            acc = __builtin_amdgcn_mfma_f32_16x16x32_f16(af, bf, acc, 0, 0, 0);
            float bx = (j < 25) ? (float)P[BXo + j] : 0.0f;
            #pragma unroll
            for (int r = 0; r < 4; r++) xv[jj][r] = acc[r] + bx;
        }
        #pragma unroll
        for (int jj = 0; jj < 4; jj++) {
            int job = wv*4 + jj, mt = job >> 1, nt = job & 1;
            int j = nt*16 + m16;
            #pragma unroll
            for (int r = 0; r < 4; r++) {
                int t = mt*16 + q*4 + r;
                h16 hv = (h16)xv[jj][r];
                if (j < 5)       P[XP5_ + t*5 + j] = hv;
                else if (j < 15) P[BS_ + (j - 5)*136 + t] = hv;
                else if (j < 25) Ch[(size_t)(b*NS + (j - 15))*L_ + l0 + t] = hv;
            }
        }
    }
    __syncthreads();   // b4

    // ---------- P4b: t-threads: uh+Bh+default-y, softmax (u row in regs) ----
    h16 urow[20];
    float dl[20];
    if (tid < 128) {
        const int t = tid;
        *(half4*)&urow[0]  = *(const half4*)&P[UL_ + t*36 + 0];
        *(half4*)&urow[4]  = *(const half4*)&P[UL_ + t*36 + 4];
        *(half4*)&urow[8]  = *(const half4*)&P[UL_ + t*36 + 8];
        *(half4*)&urow[12] = *(const half4*)&P[UL_ + t*36 + 12];
        *(half4*)&urow[16] = *(const half4*)&P[UL_ + t*36 + 16];
        #pragma unroll
        for (int d2 = 0; d2 < 20; d2++)
            uh[(size_t)(b*DI + d2)*L_ + l0 + t] = urow[d2];
        #pragma unroll
        for (int n = 0; n < NS; n++)
            Bh[(size_t)(b*NS + n)*L_ + l0 + t] = P[BS_ + n*136 + t];
        // default output y = u*D (overwritten by kD only for active chunks)
        {
            float yo[20];
            #pragma unroll
            for (int d2 = 0; d2 < 20; d2++) yo[d2] = (float)urow[d2] * D_s[d2];
            float4* ob = (float4*)(out + ((size_t)b*L_ + l0 + t)*DI);
            #pragma unroll
            for (int k4 = 0; k4 < 5; k4++)
                ob[k4] = make_float4(yo[4*k4], yo[4*k4+1], yo[4*k4+2], yo[4*k4+3]);
        }
        float xq[5];
        #pragma unroll
        for (int r = 0; r < 5; r++) xq[r] = (float)P[XP5_ + t*5 + r];
        #pragma unroll
        for (int d2 = 0; d2 < 20; d2++) dl[d2] = (float)P[BDTo + d2];
        #pragma unroll
        for (int r = 0; r < 5; r++) {
            float dv = xq[r];
            #pragma unroll
            for (int d2 = 0; d2 < 20; d2++)
                dl[d2] = fmaf(dv, (float)P[WDTo + r*20 + d2], dl[d2]);
        }
        float mx = dl[0];
        #pragma unroll
        for (int d2 = 1; d2 < 20; d2++) mx = fmaxf(mx, dl[d2]);
        float sm = 0.0f;
        #pragma unroll
        for (int d2 = 0; d2 < 20; d2++) { dl[d2] = __expf(dl[d2] - mx); sm += dl[d2]; }
        float inv = __builtin_amdgcn_rcpf(sm);
        #pragma unroll
        for (int d2 = 0; d2 < 20; d2++) dl[d2] *= inv;
    }
    __syncthreads();   // b5: UL/XP5 dead

    // ---------- P4c: DS/DUS staging + dh ----------
    if (tid < 128) {
        const int t = tid;
        #pragma unroll
        for (int d2 = 0; d2 < 20; d2++) {
            h16 dlh = (h16)dl[d2];
            P[DS__ + d2*136 + t] = dlh;
            P[DUS_ + d2*136 + t] = (h16)((float)dlh * (float)urow[d2]);
            dh[(size_t)(b*DI + d2)*L_ + l0 + t] = dlh;
        }
    }
    __syncthreads();   // b6

    // ---------- P5: chunk-local scan ----------
    const int d  = tid >> 4;
    const int s  = tid & 15;
    const int bd = b*DI + d;

    float d8[8], du8[8];
    { half8 hv = *(const half8*)&P[DS__ + d*136 + 8*s];
      #pragma unroll
      for (int j = 0; j < 8; j++) d8[j] = (float)hv[j]; }
    { half8 hv = *(const half8*)&P[DUS_ + d*136 + 8*s];
      #pragma unroll
      for (int j = 0; j < 8; j++) du8[j] = (float)hv[j]; }

    float loc8 = 0.0f;
    #pragma unroll
    for (int j = 0; j < 8; j++) loc8 += d8[j];
    float ssum = loc8;
    SUMSCAN16(ssum);
    if (s == 15) sc_ws[(size_t)bd*NCB + c] = ssum;

    float A_dn[NS];
    #pragma unroll
    for (int n = 0; n < NS; n++) A_dn[n] = ALs[d*NS + n];

    // fast path: A_dn[n] == (n+1)*A_dn[0] (holds for A = tile(arange(1..NS)))
    bool fastA = true;
    #pragma unroll
    for (int n = 1; n < NS; n++)
        fastA = fastA &&
            (fabsf(A_dn[n] - (float)(n+1)*A_dn[0]) <= 1e-3f*fabsf(A_dn[n]) + 1e-6f);

    float AcA[NS], BcA[NS];
    if (fastA) {
        float e1[8], ep[8];
        #pragma unroll
        for (int j = 0; j < 8; j++) { e1[j] = __expf(A_dn[0]*d8[j]); ep[j] = e1[j]; }
        #pragma unroll
        for (int n = 0; n < NS; n++) {
            half8 bv = *(const half8*)&P[BS_ + n*136 + 8*s];
            float Bc = 0.0f;
            #pragma unroll
            for (int j = 0; j < 8; j++)
                Bc = fmaf(ep[j], Bc, du8[j]*(float)bv[j]);
            BcA[n] = Bc;
            AcA[n] = __expf(A_dn[n]*loc8);   // closed form: prod_j exp(A d_j)
            if (n < NS-1) {
                #pragma unroll
                for (int j = 0; j < 8; j++) ep[j] *= e1[j];
            }
        }
    } else {
        #pragma unroll
        for (int n = 0; n < NS; n++) {
            half8 bv = *(const half8*)&P[BS_ + n*136 + 8*s];
            float Bc = 0.0f;
            #pragma unroll
            for (int j = 0; j < 8; j++) {
                float a = __expf(A_dn[n]*d8[j]);
                Bc = fmaf(a, Bc, du8[j]*(float)bv[j]);
            }
            BcA[n] = Bc;
            AcA[n] = __expf(A_dn[n]*loc8);
        }
    }
    #pragma unroll
    for (int n = 0; n < NS; n++) { OPSCAN16(AcA[n], BcA[n]); }
    if (s == 15) {
        const size_t o0 = ((size_t)bd*NS)*NCB + c;
        #pragma unroll
        for (int n = 0; n < NS; n++) {
            ap_ws[o0 + (size_t)n*NCB] = AcA[n];
            rs_ws[o0 + (size_t)n*NCB] = BcA[n];
        }
    }
}

// =============== kD: gate + parallel inter-chunk recompute + fixup =======
// kC2 is gone. Every block derives Tot / exclusive-prefix from raw sc_ws via
// a 16-lane segment scan (4x float4 loads + SUMSCAN16). Only ACTIVE blocks
// (~2%) recover rin[n] with the same 16-lane PARALLEL segment compose over
// raw ap/rs (contiguous float4 loads) — not R3's serial chain.
__global__ __launch_bounds__(320) void kD(
    const h16* __restrict__ dh, const h16* __restrict__ uh,
    const h16* __restrict__ Bh, const h16* __restrict__ Ch,
    const float* __restrict__ A_log, const float* __restrict__ D_param,
    const float* __restrict__ ap_ws, const float* __restrict__ rs_ws,
    const float* __restrict__ sc_ws, float* __restrict__ out)
{
    __shared__ float ylT[20*132];
    __shared__ int anyact;
    const int tid = threadIdx.x;
    const int d   = tid >> 4;
    const int s   = tid & 15;
    const int lnw = tid & 63;
    const int c   = blockIdx.x;
    const int b   = blockIdx.y;
    const int bd  = b*DI + d;
    const size_t t0 = (size_t)c*TBLK + s*8;

    // ---- Tot and exclusive chunk-prefix P(c) from raw sc_ws ----
    float totp = 0.0f, clipp = 0.0f;
    {
        const float4* sc4 = (const float4*)(sc_ws + (size_t)bd*NCB + s*16);
        #pragma unroll
        for (int q4 = 0; q4 < 4; q4++) {
            float4 v = sc4[q4];
            int base = s*16 + q4*4;
            totp  += v.x + v.y + v.z + v.w;
            clipp += (base + 0 < c ? v.x : 0.0f) + (base + 1 < c ? v.y : 0.0f)
                   + (base + 2 < c ? v.z : 0.0f) + (base + 3 < c ? v.w : 0.0f);
        }
    }
    SUMSCAN16(totp);
    SUMSCAN16(clipp);
    const float Tot = __shfl(totp,  lnw | 15);
    const float Pc  = __shfl(clipp, lnw | 15);
    const float sc_c = sc_ws[(size_t)bd*NCB + c];
    const float pref_end = Pc + sc_c;

    // cheap gate: Amax = -exp(min_n A_log)
    float mnlog = A_log[d*NS];
    #pragma unroll
    for (int n = 1; n < NS; n++) mnlog = fminf(mnlog, A_log[d*NS + n]);
    const float Amax = -__expf(mnlog);
    const bool active = fmaf(Amax, Tot - pref_end, 40.0f) > 0.0f;

    if (tid == 0) anyact = 0;
    __syncthreads();
    if (active) anyact = 1;
    __syncthreads();
    if (anyact == 0) return;        // k1's default y stands

    float u8[8];
    { half8 hv = *(const half8*)(uh + (size_t)bd*L_ + t0);
      #pragma unroll
      for (int j = 0; j < 8; j++) u8[j] = (float)hv[j]; }
    const float Dd = D_param[d];
    float yv[8];
    #pragma unroll
    for (int j = 0; j < 8; j++) yv[j] = u8[j]*Dd;

    if (active) {
        float A_dn[NS];
        #pragma unroll
        for (int n = 0; n < NS; n++) A_dn[n] = -__expf(A_log[d*NS + n]);
        bool fastA = true;
        #pragma unroll
        for (int n = 1; n < NS; n++)
            fastA = fastA &&
                (fabsf(A_dn[n] - (float)(n+1)*A_dn[0]) <= 1e-3f*fabsf(A_dn[n]) + 1e-6f);

        // ---- rin[n]: 16-lane parallel segment compose over raw ap/rs ----
        float rin[NS];
        #pragma unroll
        for (int n = 0; n < NS; n++) {
            const float4* ap4 = (const float4*)(ap_ws + ((size_t)bd*NS + n)*NCB + s*16);
            const float4* rs4 = (const float4*)(rs_ws + ((size_t)bd*NS + n)*NCB + s*16);
            float Aa = 1.0f, Bb = 0.0f;
            #pragma unroll
            for (int k4 = 0; k4 < 4; k4++) {
                float4 av = ap4[k4];
                float4 rv = rs4[k4];
                int base = s*16 + k4*4;
                if (base + 0 < c) { Bb = fmaf(av.x, Bb, rv.x); Aa *= av.x; }
                if (base + 1 < c) { Bb = fmaf(av.y, Bb, rv.y); Aa *= av.y; }
                if (base + 2 < c) { Bb = fmaf(av.z, Bb, rv.z); Aa *= av.z; }
                if (base + 3 < c) { Bb = fmaf(av.w, Bb, rv.w); Aa *= av.w; }
            }
            OPSCAN16(Aa, Bb);
            rin[n] = __shfl(Bb, lnw | 15);
        }

        float d8[8], du8[8];
        { half8 hv = *(const half8*)(dh + (size_t)bd*L_ + t0);
          #pragma unroll
          for (int j = 0; j < 8; j++) d8[j] = (float)hv[j]; }
        #pragma unroll
        for (int j = 0; j < 8; j++) du8[j] = d8[j]*u8[j];

        float lp[8];
        { float run = 0.0f;
          #pragma unroll
          for (int j = 0; j < 8; j++) { run += d8[j]; lp[j] = run; } }
        float inc = lp[7];
        SUMSCAN16(inc);
        float ex = dppf<ROW_SHR1>(0.0f, inc);
        const float basep = Pc + ex;

        float yacc[8];
        #pragma unroll
        for (int j = 0; j < 8; j++) yacc[j] = 0.0f;

        if (fastA) {
            float e1[8], ep[8];
            #pragma unroll
            for (int j = 0; j < 8; j++) { e1[j] = __expf(A_dn[0]*d8[j]); ep[j] = e1[j]; }
            #pragma unroll
            for (int n = 0; n < NS; n++) {
                half8 bv = *(const half8*)(Bh + (size_t)(b*NS + n)*L_ + t0);
                half8 cv = *(const half8*)(Ch + (size_t)(b*NS + n)*L_ + t0);
                float b8[8];
                #pragma unroll
                for (int j = 0; j < 8; j++) b8[j] = du8[j]*(float)bv[j];
                float Bc = 0.0f;
                #pragma unroll
                for (int j = 0; j < 8; j++) Bc = fmaf(ep[j], Bc, b8[j]);
                float Ac = __expf(A_dn[n]*lp[7]);
                OPSCAN16(Ac, Bc);
                float pA = dppf<ROW_SHR1>(1.0f, Ac);
                float pB = dppf<ROW_SHR1>(0.0f, Bc);
                float r  = fmaf(pA, rin[n], pB);

                float G[8];
                G[7] = __expf(A_dn[n]*(Tot - (basep + lp[7])));
                #pragma unroll
                for (int j = 6; j >= 0; j--) G[j] = G[j+1]*ep[j+1];
                #pragma unroll
                for (int j = 0; j < 8; j++) {
                    r = fmaf(ep[j], r, b8[j]);
                    float damp = G[j] * __builtin_amdgcn_rcpf(G[j] + 1e-12f);
                    yacc[j] = fmaf((float)cv[j]*damp, r, yacc[j]);
                }
                if (n < NS-1) {
                    #pragma unroll
                    for (int j = 0; j < 8; j++) ep[j] *= e1[j];
                }
            }
        } else {
            #pragma unroll 2
            for (int n = 0; n < NS; n++) {
                half8 bv = *(const half8*)(Bh + (size_t)(b*NS + n)*L_ + t0);
                half8 cv = *(const half8*)(Ch + (size_t)(b*NS + n)*L_ + t0);
                float a8[8], b8[8];
                #pragma unroll
                for (int j = 0; j < 8; j++) {
                    a8[j] = __expf(A_dn[n]*d8[j]);
                    b8[j] = du8[j]*(float)bv[j];
                }
                float Bc = 0.0f;
                #pragma unroll
                for (int j = 0; j < 8; j++) Bc = fmaf(a8[j], Bc, b8[j]);
                float Ac = __expf(A_dn[n]*lp[7]);
                OPSCAN16(Ac, Bc);
                float pA = dppf<ROW_SHR1>(1.0f, Ac);
                float pB = dppf<ROW_SHR1>(0.0f, Bc);
                float r  = fmaf(pA, rin[n], pB);

                float G[8];
                G[7] = __expf(A_dn[n]*(Tot - (basep + lp[7])));
                #pragma unroll
                for (int j = 6; j >= 0; j--) G[j] = G[j+1]*a8[j+1];
                #pragma unroll
                for (int j = 0; j < 8; j++) {
                    r = fmaf(a8[j], r, b8[j]);
                    float damp = G[j] * __builtin_amdgcn_rcpf(G[j] + 1e-12f);
                    yacc[j] = fmaf((float)cv[j]*damp, r, yacc[j]);
                }
            }
        }
        #pragma unroll
        for (int j = 0; j < 8; j++) yv[j] = fmaf(u8[j], Dd, yacc[j]);
    }

    *(float4*)&ylT[d*132 + 8*s]     = *(float4*)(yv);
    *(float4*)&ylT[d*132 + 8*s + 4] = *(float4*)(yv + 4);
    __syncthreads();

    float4* ob4 = (float4*)(out + ((size_t)b*L_ + (size_t)c*TBLK)*DI);
    for (int i = tid; i < TBLK*DI/4; i += 320) {
        int t = i / 5, qq = (i - t*5)*4;
        ob4[i] = make_float4(ylT[qq*132 + t], ylT[(qq+1)*132 + t],
                             ylT[(qq+2)*132 + t], ylT[(qq+3)*132 + t]);
    }
}

extern "C" void kernel_launch(void* const* d_in, const int* in_sizes, int n_in,
                              void* d_out, int out_size, void* d_ws, size_t ws_size,
                              hipStream_t stream) {
    const float* x      = (const float*)d_in[0];
    const float* w_in   = (const float*)d_in[1];
    const float* b_in   = (const float*)d_in[2];
    const float* conv_k = (const float*)d_in[3];
    const float* conv_b = (const float*)d_in[4];
    const float* w_x    = (const float*)d_in[5];
    const float* b_x    = (const float*)d_in[6];
    const float* w_dt   = (const float*)d_in[7];
    const float* b_dt   = (const float*)d_in[8];
    const float* A_log  = (const float*)d_in[9];
    const float* D_par  = (const float*)d_in[10];
    float* out = (float*)d_out;
    float* ws  = (float*)d_ws;

    float* ap_ws  = ws + OFF_AP;
    float* rs_ws  = ws + OFF_RS;
    float* sc_ws  = ws + OFF_SC;
    h16*   hbase  = (h16*)(ws + OFF_H16);
    h16* dh  = hbase + HD;
    h16* uh  = hbase + HU;
    h16* Bh  = hbase + HB;
    h16* Ch  = hbase + HC;

    k1<<<dim3(NCB, B_), 320, 0, stream>>>(x, w_in, b_in, conv_k, conv_b,
                                          w_x, b_x, w_dt, b_dt, A_log, D_par,
                                          dh, uh, Bh, Ch,
                                          ap_ws, rs_ws, sc_ws, out);
    kD<<<dim3(NCB, B_), 320, 0, stream>>>(dh, uh, Bh, Ch, A_log, D_par,
                                          ap_ws, rs_ws, sc_ws, out);
}

// Round 7
// 123.593 us; speedup vs baseline: 1.0524x; 1.0524x over previous
//
#include <hip/hip_runtime.h>
#include <math.h>

#define B_   4
#define L_   32768
#define DI   20
#define NS   10
#define TBLK 128          // timesteps per chunk/block
#define NCB  256          // chunks per batch

// fp32 offsets in ws (floats)
#define OFF_AP   0u
#define OFF_RS   204800u
#define OFF_SC   409600u
#define OFF_TOT  430080u
#define OFF_H16  430192u     // h16 region (16B aligned)
#define OFF_CMIN 4362352u    // 80 floats, past the h16 region
// half offsets within h16 region
#define HD  0u             // delta [80][32768]
#define HU  2621440u       // u
#define HB  5242880u       // B [40][32768]
#define HC  6553600u       // C

typedef _Float16 h16;
typedef _Float16 half8 __attribute__((ext_vector_type(8)));
typedef _Float16 half4 __attribute__((ext_vector_type(4)));
typedef float f32x4 __attribute__((ext_vector_type(4)));

// ---- DPP helpers: row_shr within 16-lane rows, OOB lanes -> identity ----
template<int CTRL>
__device__ __forceinline__ float dppf(float idv, float src) {
    union U { float f; int i; };
    U o, s, r; o.f = idv; s.f = src;
    r.i = __builtin_amdgcn_update_dpp(o.i, s.i, CTRL, 0xf, 0xf, false);
    return r.f;
}
#define ROW_SHR1 0x111
#define ROW_SHR2 0x112
#define ROW_SHR4 0x114
#define ROW_SHR8 0x118

#define OPSCAN16(Ac, Bc) \
    { float aP = dppf<ROW_SHR1>(1.0f, Ac); float bP = dppf<ROW_SHR1>(0.0f, Bc); \
      Bc = fmaf(Ac, bP, Bc); Ac *= aP; \
      aP = dppf<ROW_SHR2>(1.0f, Ac); bP = dppf<ROW_SHR2>(0.0f, Bc); \
      Bc = fmaf(Ac, bP, Bc); Ac *= aP; \
      aP = dppf<ROW_SHR4>(1.0f, Ac); bP = dppf<ROW_SHR4>(0.0f, Bc); \
      Bc = fmaf(Ac, bP, Bc); Ac *= aP; \
      aP = dppf<ROW_SHR8>(1.0f, Ac); bP = dppf<ROW_SHR8>(0.0f, Bc); \
      Bc = fmaf(Ac, bP, Bc); Ac *= aP; }

#define SUMSCAN16(v) \
    { v += dppf<ROW_SHR1>(0.0f, v); v += dppf<ROW_SHR2>(0.0f, v); \
      v += dppf<ROW_SHR4>(0.0f, v); v += dppf<ROW_SHR8>(0.0f, v); }

// ---- k1 LDS layout (halves) ----
#define XS_   0
#define MT_   2640
#define UL_   0
#define DS__  0
#define DUS_  2720
#define XP5_  4608
#define BS_   5448
#define WXo   6808
#define WDTo  7808
#define BDTo  7908
#define BXo   7928
#define POOLH 7956
#define WF_   7956         // halves offset of 1600-float scratch (phase A only)
#define POOL2 (POOLH + 3200)

// =============== k1: weight preformat + MFMA front-end + chunk scan ======
// Also writes the DEFAULT output y = u*D for its whole chunk.
__global__ __launch_bounds__(320) void k1(
    const float* __restrict__ x,
    const float* __restrict__ w_in, const float* __restrict__ b_in,
    const float* __restrict__ conv_k, const float* __restrict__ conv_b,
    const float* __restrict__ w_x, const float* __restrict__ b_x,
    const float* __restrict__ w_dt, const float* __restrict__ b_dt,
    const float* __restrict__ A_log, const float* __restrict__ D_param,
    h16* __restrict__ dh, h16* __restrict__ uh,
    h16* __restrict__ Bh, h16* __restrict__ Ch,
    float* __restrict__ ap_ws, float* __restrict__ rs_ws, float* __restrict__ sc_ws,
    float* __restrict__ out)
{
    __shared__ __align__(16) h16 P[POOL2];
    __shared__ float beff_s[20];
    __shared__ float ALs[200];     // -exp(A_log)
    __shared__ float D_s[20];

    const int tid = threadIdx.x;
    const int c   = blockIdx.x;
    const int b   = blockIdx.y;
    const int l0  = c * TBLK;

    // ---------- Phase A1: raw weights -> LDS float scratch ----------
    {
        float* Wf = (float*)&P[WF_];   // 1600 floats: w_in 20x20 @0, conv_k @400
        for (int i = tid; i < 400;  i += 320) Wf[i]       = w_in[(i/20)*40 + (i%20)];
        for (int i = tid; i < 1200; i += 320) Wf[400 + i] = conv_k[i];
        for (int i = tid; i < 200;  i += 320) ALs[i] = -__expf(A_log[i]);
        if (tid < 20) D_s[tid] = D_param[tid];
    }
    __syncthreads();

    // ---------- Phase A2: preformat weights (h16) + beff + stage x ----------
    {
        const float* Wf = (const float*)&P[WF_];
        for (int e = tid; e < 1200; e += 320) {        // MeffT [20][72]
            int cc = e/20, o = e - cc*20;
            int w = cc/20, i = cc - w*20;
            float acc = 0.0f;
            #pragma unroll
            for (int op = 0; op < 20; op++)
                acc = fmaf(Wf[i*20 + op], Wf[400 + (w*20 + op)*20 + o], acc);
            P[MT_ + o*72 + cc] = (h16)acc;
        }
        for (int i = tid; i < 240; i += 320) {          // zero MT cols 60..71
            int o = i/12, cc = 60 + (i - (i/12)*12);
            P[MT_ + o*72 + cc] = (h16)0.0f;
        }
        for (int i = tid; i < 1000; i += 320) {         // WxT[j][k=d]
            int j = i/40, k = i - j*40;
            P[WXo + i] = (k < 20) ? (h16)w_x[k*25 + j] : (h16)0.0f;
        }
        for (int i = tid; i < 100; i += 320) P[WDTo + i] = (h16)w_dt[i];
        if (tid < 20) P[BDTo + tid] = (h16)b_dt[tid];
        if (tid < 25) P[BXo + tid] = (h16)b_x[tid];
        if (tid < 20) {
            float be = conv_b[tid];
            #pragma unroll
            for (int w = 0; w < 3; w++)
                #pragma unroll
                for (int op = 0; op < 20; op++)
                    be = fmaf(b_in[op], Wf[400 + (w*20 + op)*20 + tid], be);
            beff_s[tid] = be;
        }
        // x window -> XS (does not overlap MT_/WF_)
        const float* xb = x + ((size_t)b*L_ + l0)*DI - 2*DI;
        for (int i = tid; i < 1320; i += 320) {
            float2 v;
            if (i >= 1300 || (c == 0 && i < 20)) v = make_float2(0.0f, 0.0f);
            else v = *(const float2*)(xb + 2*i);
            P[XS_ + 2*i]     = (h16)v.x;
            P[XS_ + 2*i + 1] = (h16)v.y;
        }
    }
    __syncthreads();   // b1

    // ---------- P2: u_pre = Xflat @ Meff (MFMA), +beff, silu ----------
    const int wv  = tid >> 6;
    const int ln  = tid & 63;
    const int m16 = ln & 15;
    const int q   = ln >> 4;
    float uval[4][4];
    if (wv < 4) {
        #pragma unroll
        for (int jj = 0; jj < 4; jj++) {
            int job = wv*4 + jj, mt = job >> 1, nt = job & 1;
            int t_row = mt*16 + m16;
            int dcol  = nt*16 + m16;
            int dmin  = dcol < 20 ? dcol : 19;
            f32x4 acc = {0.0f, 0.0f, 0.0f, 0.0f};
            #pragma unroll
            for (int kh = 0; kh < 2; kh++) {
                half8 af, bf;
                int ab = XS_ + t_row*20 + kh*32 + (q<<3);
                *(half4*)&af         = *(const half4*)&P[ab];
                *(((half4*)&af) + 1) = *(const half4*)&P[ab + 4];
                int bb = MT_ + dmin*72 + kh*32 + (q<<3);
                *(half4*)&bf         = *(const half4*)&P[bb];
                *(((half4*)&bf) + 1) = *(const half4*)&P[bb + 4];
                acc = __builtin_amdgcn_mfma_f32_16x16x32_f16(af, bf, acc, 0, 0, 0);
            }
            float bfv = beff_s[dmin];
            #pragma unroll
            for (int r = 0; r < 4; r++) {
                float a = acc[r] + bfv;
                uval[jj][r] = a * __builtin_amdgcn_rcpf(1.0f + __expf(-a));
            }
        }
    }
    __syncthreads();   // b2: XS dead -> UL may overwrite

    if (wv < 4) {
        #pragma unroll
        for (int jj = 0; jj < 4; jj++) {
            int job = wv*4 + jj, mt = job >> 1, nt = job & 1;
            int dcol = nt*16 + m16;
            if (dcol < 20) {
                #pragma unroll
                for (int r = 0; r < 4; r++)
                    P[UL_ + (mt*16 + q*4 + r)*36 + dcol] = (h16)uval[jj][r];
            }
        }
    }
    __syncthreads();   // b3

    // ---------- P3: xp = u @ w_x (MFMA), +b_x; stash XP5/BS; Ch direct ----------
    float xv[4][4];
    if (wv < 4) {
        #pragma unroll
        for (int jj = 0; jj < 4; jj++) {
            int job = wv*4 + jj, mt = job >> 1, nt = job & 1;
            int t_row = mt*16 + m16;
            int j     = nt*16 + m16;
            int jmin  = j < 25 ? j : 24;
            f32x4 acc = {0.0f, 0.0f, 0.0f, 0.0f};
            half8 af, bf;
            int ab = UL_ + t_row*36 + (q<<3);
            *(half4*)&af         = *(const half4*)&P[ab];
            *(((half4*)&af) + 1) = *(const half4*)&P[ab + 4];
            int bb = WXo + jmin*40 + (q<<3);
            *(half4*)&bf         = *(const half4*)&P[bb];
            *(((half4*)&bf) + 1) = *(const half4*)&P[bb + 4];
            acc = __builtin_amdgcn_mfma_f32_16x16x32_f16(af, bf, acc, 0, 0, 0);
            float bx = (j < 25) ? (float)P[BXo + j] : 0.0f;
            #pragma unroll
            for (int r = 0; r < 4; r++) xv[jj][r] = acc[r] + bx;
        }
        #pragma unroll
        for (int jj = 0; jj < 4; jj++) {
            int job = wv*4 + jj, mt = job >> 1, nt = job & 1;
            int j = nt*16 + m16;
            #pragma unroll
            for (int r = 0; r < 4; r++) {
                int t = mt*16 + q*4 + r;
                h16 hv = (h16)xv[jj][r];
                if (j < 5)       P[XP5_ + t*5 + j] = hv;
                else if (j < 15) P[BS_ + (j - 5)*136 + t] = hv;
                else if (j < 25) Ch[(size_t)(b*NS + (j - 15))*L_ + l0 + t] = hv;
            }
        }
    }
    __syncthreads();   // b4

    // ---------- P4b: t-threads: uh+Bh+default-y, softmax (u row in regs) ----
    h16 urow[20];
    float dl[20];
    if (tid < 128) {
        const int t = tid;
        *(half4*)&urow[0]  = *(const half4*)&P[UL_ + t*36 + 0];
        *(half4*)&urow[4]  = *(const half4*)&P[UL_ + t*36 + 4];
        *(half4*)&urow[8]  = *(const half4*)&P[UL_ + t*36 + 8];
        *(half4*)&urow[12] = *(const half4*)&P[UL_ + t*36 + 12];
        *(half4*)&urow[16] = *(const half4*)&P[UL_ + t*36 + 16];
        #pragma unroll
        for (int d2 = 0; d2 < 20; d2++)
            uh[(size_t)(b*DI + d2)*L_ + l0 + t] = urow[d2];
        #pragma unroll
        for (int n = 0; n < NS; n++)
            Bh[(size_t)(b*NS + n)*L_ + l0 + t] = P[BS_ + n*136 + t];
        // default output y = u*D (overwritten by kD only for active chunks)
        {
            float yo[20];
            #pragma unroll
            for (int d2 = 0; d2 < 20; d2++) yo[d2] = (float)urow[d2] * D_s[d2];
            float4* ob = (float4*)(out + ((size_t)b*L_ + l0 + t)*DI);
            #pragma unroll
            for (int k4 = 0; k4 < 5; k4++)
                ob[k4] = make_float4(yo[4*k4], yo[4*k4+1], yo[4*k4+2], yo[4*k4+3]);
        }
        float xq[5];
        #pragma unroll
        for (int r = 0; r < 5; r++) xq[r] = (float)P[XP5_ + t*5 + r];
        #pragma unroll
        for (int d2 = 0; d2 < 20; d2++) dl[d2] = (float)P[BDTo + d2];
        #pragma unroll
        for (int r = 0; r < 5; r++) {
            float dv = xq[r];
            #pragma unroll
            for (int d2 = 0; d2 < 20; d2++)
                dl[d2] = fmaf(dv, (float)P[WDTo + r*20 + d2], dl[d2]);
        }
        float mx = dl[0];
        #pragma unroll
        for (int d2 = 1; d2 < 20; d2++) mx = fmaxf(mx, dl[d2]);
        float sm = 0.0f;
        #pragma unroll
        for (int d2 = 0; d2 < 20; d2++) { dl[d2] = __expf(dl[d2] - mx); sm += dl[d2]; }
        float inv = __builtin_amdgcn_rcpf(sm);
        #pragma unroll
        for (int d2 = 0; d2 < 20; d2++) dl[d2] *= inv;
    }
    __syncthreads();   // b5: UL/XP5 dead

    // ---------- P4c: DS/DUS staging + dh ----------
    if (tid < 128) {
        const int t = tid;
        #pragma unroll
        for (int d2 = 0; d2 < 20; d2++) {
            h16 dlh = (h16)dl[d2];
            P[DS__ + d2*136 + t] = dlh;
            P[DUS_ + d2*136 + t] = (h16)((float)dlh * (float)urow[d2]);
            dh[(size_t)(b*DI + d2)*L_ + l0 + t] = dlh;
        }
    }
    __syncthreads();   // b6

    // ---------- P5: chunk-local scan ----------
    const int d  = tid >> 4;
    const int s  = tid & 15;
    const int bd = b*DI + d;

    float d8[8], du8[8];
    { half8 hv = *(const half8*)&P[DS__ + d*136 + 8*s];
      #pragma unroll
      for (int j = 0; j < 8; j++) d8[j] = (float)hv[j]; }
    { half8 hv = *(const half8*)&P[DUS_ + d*136 + 8*s];
      #pragma unroll
      for (int j = 0; j < 8; j++) du8[j] = (float)hv[j]; }

    float loc8 = 0.0f;
    #pragma unroll
    for (int j = 0; j < 8; j++) loc8 += d8[j];
    float ssum = loc8;
    SUMSCAN16(ssum);
    if (s == 15) sc_ws[(size_t)bd*NCB + c] = ssum;

    float A_dn[NS];
    #pragma unroll
    for (int n = 0; n < NS; n++) A_dn[n] = ALs[d*NS + n];

    // fast path: A_dn[n] == (n+1)*A_dn[0]
    bool fastA = true;
    #pragma unroll
    for (int n = 1; n < NS; n++)
        fastA = fastA &&
            (fabsf(A_dn[n] - (float)(n+1)*A_dn[0]) <= 1e-3f*fabsf(A_dn[n]) + 1e-6f);

    float AcA[NS], BcA[NS];
    if (fastA) {
        float e1[8], ep[8];
        #pragma unroll
        for (int j = 0; j < 8; j++) { e1[j] = __expf(A_dn[0]*d8[j]); ep[j] = e1[j]; }
        #pragma unroll
        for (int n = 0; n < NS; n++) {
            half8 bv = *(const half8*)&P[BS_ + n*136 + 8*s];
            float Bc = 0.0f;
            #pragma unroll
            for (int j = 0; j < 8; j++)
                Bc = fmaf(ep[j], Bc, du8[j]*(float)bv[j]);
            BcA[n] = Bc;
            AcA[n] = __expf(A_dn[n]*loc8);
            if (n < NS-1) {
                #pragma unroll
                for (int j = 0; j < 8; j++) ep[j] *= e1[j];
            }
        }
    } else {
        #pragma unroll
        for (int n = 0; n < NS; n++) {
            half8 bv = *(const half8*)&P[BS_ + n*136 + 8*s];
            float Bc = 0.0f;
            #pragma unroll
            for (int j = 0; j < 8; j++) {
                float a = __expf(A_dn[n]*d8[j]);
                Bc = fmaf(a, Bc, du8[j]*(float)bv[j]);
            }
            BcA[n] = Bc;
            AcA[n] = __expf(A_dn[n]*loc8);
        }
    }
    #pragma unroll
    for (int n = 0; n < NS; n++) { OPSCAN16(AcA[n], BcA[n]); }
    if (s == 15) {
        const size_t o0 = ((size_t)bd*NS)*NCB + c;
        #pragma unroll
        for (int n = 0; n < NS; n++) {
            ap_ws[o0 + (size_t)n*NCB] = AcA[n];
            rs_ws[o0 + (size_t)n*NCB] = BcA[n];
        }
    }
}

// =============== kC2: inter-chunk scan + first-active-chunk (cmin) ========
__global__ __launch_bounds__(64) void kC2(
    const float* __restrict__ ap_ws, float* __restrict__ rs_ws,
    float* __restrict__ sc_ws, float* __restrict__ tot_ws,
    const float* __restrict__ A_log, float* __restrict__ cmin_ws)
{
    const int bd   = blockIdx.x;
    const int lane = threadIdx.x;
    const size_t sb = (size_t)bd*NCB + lane*4;

    float4 sv = *(const float4*)(sc_ws + sb);
    float l1 = sv.x, l2 = l1 + sv.y, l3 = l2 + sv.z, l4 = l3 + sv.w;
    float inc = l4;
    #pragma unroll
    for (int off = 1; off < 64; off <<= 1) {
        float t = __shfl_up(inc, off);
        if (lane >= off) inc += t;
    }
    float ex = __shfl_up(inc, 1);
    if (lane == 0) ex = 0.0f;
    *(float4*)(sc_ws + sb) = make_float4(ex, ex + l1, ex + l2, ex + l3);
    if (lane == 63) tot_ws[bd] = inc;

    // ---- first active chunk: gate is monotonic in c ----
    {
        const float TotAll = __shfl(inc, 63);
        const int dd = bd % DI;
        float mnlog = A_log[dd*NS];
        #pragma unroll
        for (int n = 1; n < NS; n++) mnlog = fminf(mnlog, A_log[dd*NS + n]);
        const float Amax = -__expf(mnlog);
        int cand = 100000;
        if (fmaf(Amax, TotAll - (ex + l4), 40.0f) > 0.0f) cand = lane*4 + 3;
        if (fmaf(Amax, TotAll - (ex + l3), 40.0f) > 0.0f) cand = lane*4 + 2;
        if (fmaf(Amax, TotAll - (ex + l2), 40.0f) > 0.0f) cand = lane*4 + 1;
        if (fmaf(Amax, TotAll - (ex + l1), 40.0f) > 0.0f) cand = lane*4 + 0;
        #pragma unroll
        for (int off = 32; off > 0; off >>= 1)
            cand = min(cand, __shfl_xor(cand, off));
        if (lane == 0) cmin_ws[bd] = (float)cand;
    }

    #pragma unroll 2
    for (int n = 0; n < NS; n++) {
        const size_t base = ((size_t)bd*NS + n)*NCB + lane*4;
        float4 av = *(const float4*)(ap_ws + base);
        float4 rv = *(const float4*)(rs_ws + base);
        float Ac = av.x, Bc = rv.x;
        Bc = fmaf(av.y, Bc, rv.y); Ac *= av.y;
        Bc = fmaf(av.z, Bc, rv.z); Ac *= av.z;
        Bc = fmaf(av.w, Bc, rv.w); Ac *= av.w;
        #pragma unroll
        for (int off = 1; off < 64; off <<= 1) {
            float aP = __shfl_up(Ac, off);
            float bP = __shfl_up(Bc, off);
            if (lane >= off) { Bc = fmaf(Ac, bP, Bc); Ac *= aP; }
        }
        float pB = __shfl_up(Bc, 1);
        if (lane == 0) pB = 0.0f;
        float r  = pB;
        float o0 = r; r = fmaf(av.x, r, rv.x);
        float o1 = r; r = fmaf(av.y, r, rv.y);
        float o2 = r; r = fmaf(av.z, r, rv.z);
        float o3 = r;
        *(float4*)(rs_ws + base) = make_float4(o0, o1, o2, o3);
    }
}

// =============== kD: cmin-gated fixup; bulk-loaded active path ===========
__global__ __launch_bounds__(320) void kD(
    const h16* __restrict__ dh, const h16* __restrict__ uh,
    const h16* __restrict__ Bh, const h16* __restrict__ Ch,
    const float* __restrict__ A_log, const float* __restrict__ D_param,
    const float* __restrict__ rs_ws, const float* __restrict__ sc_ws,
    const float* __restrict__ tot_ws, const float* __restrict__ cmin_ws,
    float* __restrict__ out)
{
    __shared__ float ylT[20*132];
    __shared__ int anyact;
    const int tid = threadIdx.x;
    const int d   = tid >> 4;
    const int s   = tid & 15;
    const int c   = blockIdx.x;
    const int b   = blockIdx.y;
    const int bd  = b*DI + d;
    const size_t t0 = (size_t)c*TBLK + s*8;

    // gate: ONE load (precomputed in kC2)
    const bool active = (c >= (int)cmin_ws[bd]);

    if (tid == 0) anyact = 0;
    __syncthreads();
    if (active) anyact = 1;
    __syncthreads();
    if (anyact == 0) return;        // k1's default y stands

    float u8[8];
    { half8 hv = *(const half8*)(uh + (size_t)bd*L_ + t0);
      #pragma unroll
      for (int j = 0; j < 8; j++) u8[j] = (float)hv[j]; }
    const float Dd = D_param[d];
    float yv[8];
    #pragma unroll
    for (int j = 0; j < 8; j++) yv[j] = u8[j]*Dd;

    if (active) {
        // ======== bulk load phase: issue EVERYTHING before computing ========
        half8 dvv = *(const half8*)(dh + (size_t)bd*L_ + t0);
        half8 bvA[NS], cvA[NS];
        #pragma unroll
        for (int n = 0; n < NS; n++) {
            bvA[n] = *(const half8*)(Bh + (size_t)(b*NS + n)*L_ + t0);
            cvA[n] = *(const half8*)(Ch + (size_t)(b*NS + n)*L_ + t0);
        }
        float rin[NS];
        #pragma unroll
        for (int n = 0; n < NS; n++) rin[n] = rs_ws[((size_t)bd*NS + n)*NCB + c];
        const float Tot = tot_ws[bd];
        const float scc = sc_ws[(size_t)bd*NCB + c];
        float A_dn[NS];
        #pragma unroll
        for (int n = 0; n < NS; n++) A_dn[n] = -__expf(A_log[d*NS + n]);

        bool fastA = true;
        #pragma unroll
        for (int n = 1; n < NS; n++)
            fastA = fastA &&
                (fabsf(A_dn[n] - (float)(n+1)*A_dn[0]) <= 1e-3f*fabsf(A_dn[n]) + 1e-6f);

        float d8[8], du8[8];
        #pragma unroll
        for (int j = 0; j < 8; j++) { d8[j] = (float)dvv[j]; du8[j] = d8[j]*u8[j]; }

        float lp[8];
        { float run = 0.0f;
          #pragma unroll
          for (int j = 0; j < 8; j++) { run += d8[j]; lp[j] = run; } }
        float inc = lp[7];
        SUMSCAN16(inc);
        float ex = dppf<ROW_SHR1>(0.0f, inc);
        const float basep = scc + ex;

        float yacc[8];
        #pragma unroll
        for (int j = 0; j < 8; j++) yacc[j] = 0.0f;

        if (fastA) {
            float e1[8], ep[8];
            #pragma unroll
            for (int j = 0; j < 8; j++) { e1[j] = __expf(A_dn[0]*d8[j]); ep[j] = e1[j]; }
            #pragma unroll
            for (int n = 0; n < NS; n++) {
                float b8[8];
                #pragma unroll
                for (int j = 0; j < 8; j++) b8[j] = du8[j]*(float)bvA[n][j];
                float Bc = 0.0f;
                #pragma unroll
                for (int j = 0; j < 8; j++) Bc = fmaf(ep[j], Bc, b8[j]);
                float Ac = __expf(A_dn[n]*lp[7]);
                OPSCAN16(Ac, Bc);
                float pA = dppf<ROW_SHR1>(1.0f, Ac);
                float pB = dppf<ROW_SHR1>(0.0f, Bc);
                float r  = fmaf(pA, rin[n], pB);

                float G[8];
                G[7] = __expf(A_dn[n]*(Tot - (basep + lp[7])));
                #pragma unroll
                for (int j = 6; j >= 0; j--) G[j] = G[j+1]*ep[j+1];
                #pragma unroll
                for (int j = 0; j < 8; j++) {
                    r = fmaf(ep[j], r, b8[j]);
                    float damp = G[j] * __builtin_amdgcn_rcpf(G[j] + 1e-12f);
                    yacc[j] = fmaf((float)cvA[n][j]*damp, r, yacc[j]);
                }
                if (n < NS-1) {
                    #pragma unroll
                    for (int j = 0; j < 8; j++) ep[j] *= e1[j];
                }
            }
        } else {
            #pragma unroll 2
            for (int n = 0; n < NS; n++) {
                float a8[8], b8[8];
                #pragma unroll
                for (int j = 0; j < 8; j++) {
                    a8[j] = __expf(A_dn[n]*d8[j]);
                    b8[j] = du8[j]*(float)bvA[n][j];
                }
                float Bc = 0.0f;
                #pragma unroll
                for (int j = 0; j < 8; j++) Bc = fmaf(a8[j], Bc, b8[j]);
                float Ac = __expf(A_dn[n]*lp[7]);
                OPSCAN16(Ac, Bc);
                float pA = dppf<ROW_SHR1>(1.0f, Ac);
                float pB = dppf<ROW_SHR1>(0.0f, Bc);
                float r  = fmaf(pA, rin[n], pB);

                float G[8];
                G[7] = __expf(A_dn[n]*(Tot - (basep + lp[7])));
                #pragma unroll
                for (int j = 6; j >= 0; j--) G[j] = G[j+1]*a8[j+1];
                #pragma unroll
                for (int j = 0; j < 8; j++) {
                    r = fmaf(a8[j], r, b8[j]);
                    float damp = G[j] * __builtin_amdgcn_rcpf(G[j] + 1e-12f);
                    yacc[j] = fmaf((float)cvA[n][j]*damp, r, yacc[j]);
                }
            }
        }
        #pragma unroll
        for (int j = 0; j < 8; j++) yv[j] = fmaf(u8[j], Dd, yacc[j]);
    }

    *(float4*)&ylT[d*132 + 8*s]     = *(float4*)(yv);
    *(float4*)&ylT[d*132 + 8*s + 4] = *(float4*)(yv + 4);
    __syncthreads();

    float4* ob4 = (float4*)(out + ((size_t)b*L_ + (size_t)c*TBLK)*DI);
    for (int i = tid; i < TBLK*DI/4; i += 320) {
        int t = i / 5, qq = (i - t*5)*4;
        ob4[i] = make_float4(ylT[qq*132 + t], ylT[(qq+1)*132 + t],
                             ylT[(qq+2)*132 + t], ylT[(qq+3)*132 + t]);
    }
}

extern "C" void kernel_launch(void* const* d_in, const int* in_sizes, int n_in,
                              void* d_out, int out_size, void* d_ws, size_t ws_size,
                              hipStream_t stream) {
    const float* x      = (const float*)d_in[0];
    const float* w_in   = (const float*)d_in[1];
    const float* b_in   = (const float*)d_in[2];
    const float* conv_k = (const float*)d_in[3];
    const float* conv_b = (const float*)d_in[4];
    const float* w_x    = (const float*)d_in[5];
    const float* b_x    = (const float*)d_in[6];
    const float* w_dt   = (const float*)d_in[7];
    const float* b_dt   = (const float*)d_in[8];
    const float* A_log  = (const float*)d_in[9];
    const float* D_par  = (const float*)d_in[10];
    float* out = (float*)d_out;
    float* ws  = (float*)d_ws;

    float* ap_ws   = ws + OFF_AP;
    float* rs_ws   = ws + OFF_RS;
    float* sc_ws   = ws + OFF_SC;
    float* tot_ws  = ws + OFF_TOT;
    float* cmin_ws = ws + OFF_CMIN;
    h16*   hbase   = (h16*)(ws + OFF_H16);
    h16* dh  = hbase + HD;
    h16* uh  = hbase + HU;
    h16* Bh  = hbase + HB;
    h16* Ch  = hbase + HC;

    k1<<<dim3(NCB, B_), 320, 0, stream>>>(x, w_in, b_in, conv_k, conv_b,
                                          w_x, b_x, w_dt, b_dt, A_log, D_par,
                                          dh, uh, Bh, Ch,
                                          ap_ws, rs_ws, sc_ws, out);
    kC2<<<B_*DI, 64, 0, stream>>>(ap_ws, rs_ws, sc_ws, tot_ws, A_log, cmin_ws);
    kD<<<dim3(NCB, B_), 320, 0, stream>>>(dh, uh, Bh, Ch, A_log, D_par,
                                          rs_ws, sc_ws, tot_ws, cmin_ws, out);
}

// Round 8
// 104.624 us; speedup vs baseline: 1.2432x; 1.1813x over previous
//
#include <hip/hip_runtime.h>
#include <math.h>

#define B_   4
#define L_   32768
#define DI   20
#define NS   10
#define TBLK 128          // timesteps per chunk/block
#define NCB  256          // chunks per batch

// fp32 offsets in ws (floats)
#define OFF_AP   0u
#define OFF_RS   204800u
#define OFF_SC   409600u
#define OFF_H16  430192u   // h16 region (16B aligned)
// half offsets within h16 region
#define HD  0u             // delta [80][32768]
#define HU  2621440u       // u
#define HB  5242880u       // B [40][32768]
#define HC  6553600u       // C

typedef _Float16 h16;
typedef _Float16 half8 __attribute__((ext_vector_type(8)));
typedef _Float16 half4 __attribute__((ext_vector_type(4)));
typedef float f32x4 __attribute__((ext_vector_type(4)));

// ---- DPP helpers: row_shr within 16-lane rows, OOB lanes -> identity ----
template<int CTRL>
__device__ __forceinline__ float dppf(float idv, float src) {
    union U { float f; int i; };
    U o, s, r; o.f = idv; s.f = src;
    r.i = __builtin_amdgcn_update_dpp(o.i, s.i, CTRL, 0xf, 0xf, false);
    return r.f;
}
#define ROW_SHR1 0x111
#define ROW_SHR2 0x112
#define ROW_SHR4 0x114
#define ROW_SHR8 0x118

#define OPSCAN16(Ac, Bc) \
    { float aP = dppf<ROW_SHR1>(1.0f, Ac); float bP = dppf<ROW_SHR1>(0.0f, Bc); \
      Bc = fmaf(Ac, bP, Bc); Ac *= aP; \
      aP = dppf<ROW_SHR2>(1.0f, Ac); bP = dppf<ROW_SHR2>(0.0f, Bc); \
      Bc = fmaf(Ac, bP, Bc); Ac *= aP; \
      aP = dppf<ROW_SHR4>(1.0f, Ac); bP = dppf<ROW_SHR4>(0.0f, Bc); \
      Bc = fmaf(Ac, bP, Bc); Ac *= aP; \
      aP = dppf<ROW_SHR8>(1.0f, Ac); bP = dppf<ROW_SHR8>(0.0f, Bc); \
      Bc = fmaf(Ac, bP, Bc); Ac *= aP; }

#define SUMSCAN16(v) \
    { v += dppf<ROW_SHR1>(0.0f, v); v += dppf<ROW_SHR2>(0.0f, v); \
      v += dppf<ROW_SHR4>(0.0f, v); v += dppf<ROW_SHR8>(0.0f, v); }

// ---- k1 LDS layout (halves) ----
#define XS_   0
#define MT_   2640
#define UL_   0
#define DS__  0
#define DUS_  2720
#define XP5_  4608
#define BS_   5448
#define WXo   6808
#define WDTo  7808
#define BDTo  7908
#define BXo   7928
#define POOLH 7956
#define WF_   7956         // halves offset of 1600-float scratch (phase A only)
#define POOL2 (POOLH + 3200)

// =============== k1: weight preformat + MFMA front-end + chunk scan ======
// Also writes the DEFAULT output y = u*D for its whole chunk.
__global__ __launch_bounds__(320) void k1(
    const float* __restrict__ x,
    const float* __restrict__ w_in, const float* __restrict__ b_in,
    const float* __restrict__ conv_k, const float* __restrict__ conv_b,
    const float* __restrict__ w_x, const float* __restrict__ b_x,
    const float* __restrict__ w_dt, const float* __restrict__ b_dt,
    const float* __restrict__ A_log, const float* __restrict__ D_param,
    h16* __restrict__ dh, h16* __restrict__ uh,
    h16* __restrict__ Bh, h16* __restrict__ Ch,
    float* __restrict__ ap_ws, float* __restrict__ rs_ws, float* __restrict__ sc_ws,
    float* __restrict__ out)
{
    __shared__ __align__(16) h16 P[POOL2];
    __shared__ float beff_s[20];
    __shared__ float ALs[200];     // -exp(A_log)
    __shared__ float D_s[20];

    const int tid = threadIdx.x;
    const int c   = blockIdx.x;
    const int b   = blockIdx.y;
    const int l0  = c * TBLK;

    // ---------- Phase A1: raw weights -> LDS float scratch ----------
    {
        float* Wf = (float*)&P[WF_];   // 1600 floats: w_in 20x20 @0, conv_k @400
        for (int i = tid; i < 400;  i += 320) Wf[i]       = w_in[(i/20)*40 + (i%20)];
        for (int i = tid; i < 1200; i += 320) Wf[400 + i] = conv_k[i];
        for (int i = tid; i < 200;  i += 320) ALs[i] = -__expf(A_log[i]);
        if (tid < 20) D_s[tid] = D_param[tid];
    }
    __syncthreads();

    // ---------- Phase A2: preformat weights (h16) + beff + stage x ----------
    {
        const float* Wf = (const float*)&P[WF_];
        for (int e = tid; e < 1200; e += 320) {        // MeffT [20][72]
            int cc = e/20, o = e - cc*20;
            int w = cc/20, i = cc - w*20;
            float acc = 0.0f;
            #pragma unroll
            for (int op = 0; op < 20; op++)
                acc = fmaf(Wf[i*20 + op], Wf[400 + (w*20 + op)*20 + o], acc);
            P[MT_ + o*72 + cc] = (h16)acc;
        }
        for (int i = tid; i < 240; i += 320) {          // zero MT cols 60..71
            int o = i/12, cc = 60 + (i - (i/12)*12);
            P[MT_ + o*72 + cc] = (h16)0.0f;
        }
        for (int i = tid; i < 1000; i += 320) {         // WxT[j][k=d]
            int j = i/40, k = i - j*40;
            P[WXo + i] = (k < 20) ? (h16)w_x[k*25 + j] : (h16)0.0f;
        }
        for (int i = tid; i < 100; i += 320) P[WDTo + i] = (h16)w_dt[i];
        if (tid < 20) P[BDTo + tid] = (h16)b_dt[tid];
        if (tid < 25) P[BXo + tid] = (h16)b_x[tid];
        if (tid < 20) {
            float be = conv_b[tid];
            #pragma unroll
            for (int w = 0; w < 3; w++)
                #pragma unroll
                for (int op = 0; op < 20; op++)
                    be = fmaf(b_in[op], Wf[400 + (w*20 + op)*20 + tid], be);
            beff_s[tid] = be;
        }
        // x window -> XS (does not overlap MT_/WF_)
        const float* xb = x + ((size_t)b*L_ + l0)*DI - 2*DI;
        for (int i = tid; i < 1320; i += 320) {
            float2 v;
            if (i >= 1300 || (c == 0 && i < 20)) v = make_float2(0.0f, 0.0f);
            else v = *(const float2*)(xb + 2*i);
            P[XS_ + 2*i]     = (h16)v.x;
            P[XS_ + 2*i + 1] = (h16)v.y;
        }
    }
    __syncthreads();   // b1

    // ---------- P2: u_pre = Xflat @ Meff (MFMA), +beff, silu ----------
    const int wv  = tid >> 6;
    const int ln  = tid & 63;
    const int m16 = ln & 15;
    const int q   = ln >> 4;
    float uval[4][4];
    if (wv < 4) {
        #pragma unroll
        for (int jj = 0; jj < 4; jj++) {
            int job = wv*4 + jj, mt = job >> 1, nt = job & 1;
            int t_row = mt*16 + m16;
            int dcol  = nt*16 + m16;
            int dmin  = dcol < 20 ? dcol : 19;
            f32x4 acc = {0.0f, 0.0f, 0.0f, 0.0f};
            #pragma unroll
            for (int kh = 0; kh < 2; kh++) {
                half8 af, bf;
                int ab = XS_ + t_row*20 + kh*32 + (q<<3);
                *(half4*)&af         = *(const half4*)&P[ab];
                *(((half4*)&af) + 1) = *(const half4*)&P[ab + 4];
                int bb = MT_ + dmin*72 + kh*32 + (q<<3);
                *(half4*)&bf         = *(const half4*)&P[bb];
                *(((half4*)&bf) + 1) = *(const half4*)&P[bb + 4];
                acc = __builtin_amdgcn_mfma_f32_16x16x32_f16(af, bf, acc, 0, 0, 0);
            }
            float bfv = beff_s[dmin];
            #pragma unroll
            for (int r = 0; r < 4; r++) {
                float a = acc[r] + bfv;
                uval[jj][r] = a * __builtin_amdgcn_rcpf(1.0f + __expf(-a));
            }
        }
    }
    __syncthreads();   // b2: XS dead -> UL may overwrite

    if (wv < 4) {
        #pragma unroll
        for (int jj = 0; jj < 4; jj++) {
            int job = wv*4 + jj, mt = job >> 1, nt = job & 1;
            int dcol = nt*16 + m16;
            if (dcol < 20) {
                #pragma unroll
                for (int r = 0; r < 4; r++)
                    P[UL_ + (mt*16 + q*4 + r)*36 + dcol] = (h16)uval[jj][r];
            }
        }
    }
    __syncthreads();   // b3

    // ---------- P3: xp = u @ w_x (MFMA), +b_x; stash XP5/BS; Ch direct ----------
    float xv[4][4];
    if (wv < 4) {
        #pragma unroll
        for (int jj = 0; jj < 4; jj++) {
            int job = wv*4 + jj, mt = job >> 1, nt = job & 1;
            int t_row = mt*16 + m16;
            int j     = nt*16 + m16;
            int jmin  = j < 25 ? j : 24;
            f32x4 acc = {0.0f, 0.0f, 0.0f, 0.0f};
            half8 af, bf;
            int ab = UL_ + t_row*36 + (q<<3);
            *(half4*)&af         = *(const half4*)&P[ab];
            *(((half4*)&af) + 1) = *(const half4*)&P[ab + 4];
            int bb = WXo + jmin*40 + (q<<3);
            *(half4*)&bf         = *(const half4*)&P[bb];
            *(((half4*)&bf) + 1) = *(const half4*)&P[bb + 4];
            acc = __builtin_amdgcn_mfma_f32_16x16x32_f16(af, bf, acc, 0, 0, 0);
            float bx = (j < 25) ? (float)P[BXo + j] : 0.0f;
            #pragma unroll
            for (int r = 0; r < 4; r++) xv[jj][r] = acc[r] + bx;
        }
        #pragma unroll
        for (int jj = 0; jj < 4; jj++) {
            int job = wv*4 + jj, mt = job >> 1, nt = job & 1;
            int j = nt*16 + m16;
            #pragma unroll
            for (int r = 0; r < 4; r++) {
                int t = mt*16 + q*4 + r;
                h16 hv = (h16)xv[jj][r];
                if (j < 5)       P[XP5_ + t*5 + j] = hv;
                else if (j < 15) P[BS_ + (j - 5)*136 + t] = hv;
                else if (j < 25) Ch[(size_t)(b*NS + (j - 15))*L_ + l0 + t] = hv;
            }
        }
    }
    __syncthreads();   // b4

    // ---------- P4b: t-threads: uh+Bh+default-y, softmax (u row in regs) ----
    h16 urow[20];
    float dl[20];
    if (tid < 128) {
        const int t = tid;
        *(half4*)&urow[0]  = *(const half4*)&P[UL_ + t*36 + 0];
        *(half4*)&urow[4]  = *(const half4*)&P[UL_ + t*36 + 4];
        *(half4*)&urow[8]  = *(const half4*)&P[UL_ + t*36 + 8];
        *(half4*)&urow[12] = *(const half4*)&P[UL_ + t*36 + 12];
        *(half4*)&urow[16] = *(const half4*)&P[UL_ + t*36 + 16];
        #pragma unroll
        for (int d2 = 0; d2 < 20; d2++)
            uh[(size_t)(b*DI + d2)*L_ + l0 + t] = urow[d2];
        #pragma unroll
        for (int n = 0; n < NS; n++)
            Bh[(size_t)(b*NS + n)*L_ + l0 + t] = P[BS_ + n*136 + t];
        // default output y = u*D (overwritten by kC3 only for active chunks)
        {
            float yo[20];
            #pragma unroll
            for (int d2 = 0; d2 < 20; d2++) yo[d2] = (float)urow[d2] * D_s[d2];
            float4* ob = (float4*)(out + ((size_t)b*L_ + l0 + t)*DI);
            #pragma unroll
            for (int k4 = 0; k4 < 5; k4++)
                ob[k4] = make_float4(yo[4*k4], yo[4*k4+1], yo[4*k4+2], yo[4*k4+3]);
        }
        float xq[5];
        #pragma unroll
        for (int r = 0; r < 5; r++) xq[r] = (float)P[XP5_ + t*5 + r];
        #pragma unroll
        for (int d2 = 0; d2 < 20; d2++) dl[d2] = (float)P[BDTo + d2];
        #pragma unroll
        for (int r = 0; r < 5; r++) {
            float dv = xq[r];
            #pragma unroll
            for (int d2 = 0; d2 < 20; d2++)
                dl[d2] = fmaf(dv, (float)P[WDTo + r*20 + d2], dl[d2]);
        }
        float mx = dl[0];
        #pragma unroll
        for (int d2 = 1; d2 < 20; d2++) mx = fmaxf(mx, dl[d2]);
        float sm = 0.0f;
        #pragma unroll
        for (int d2 = 0; d2 < 20; d2++) { dl[d2] = __expf(dl[d2] - mx); sm += dl[d2]; }
        float inv = __builtin_amdgcn_rcpf(sm);
        #pragma unroll
        for (int d2 = 0; d2 < 20; d2++) dl[d2] *= inv;
    }
    __syncthreads();   // b5: UL/XP5 dead

    // ---------- P4c: DS/DUS staging + dh ----------
    if (tid < 128) {
        const int t = tid;
        #pragma unroll
        for (int d2 = 0; d2 < 20; d2++) {
            h16 dlh = (h16)dl[d2];
            P[DS__ + d2*136 + t] = dlh;
            P[DUS_ + d2*136 + t] = (h16)((float)dlh * (float)urow[d2]);
            dh[(size_t)(b*DI + d2)*L_ + l0 + t] = dlh;
        }
    }
    __syncthreads();   // b6

    // ---------- P5: chunk-local scan ----------
    const int d  = tid >> 4;
    const int s  = tid & 15;
    const int bd = b*DI + d;

    float d8[8], du8[8];
    { half8 hv = *(const half8*)&P[DS__ + d*136 + 8*s];
      #pragma unroll
      for (int j = 0; j < 8; j++) d8[j] = (float)hv[j]; }
    { half8 hv = *(const half8*)&P[DUS_ + d*136 + 8*s];
      #pragma unroll
      for (int j = 0; j < 8; j++) du8[j] = (float)hv[j]; }

    float loc8 = 0.0f;
    #pragma unroll
    for (int j = 0; j < 8; j++) loc8 += d8[j];
    float ssum = loc8;
    SUMSCAN16(ssum);
    if (s == 15) sc_ws[(size_t)bd*NCB + c] = ssum;

    float A_dn[NS];
    #pragma unroll
    for (int n = 0; n < NS; n++) A_dn[n] = ALs[d*NS + n];

    // fast path: A_dn[n] == (n+1)*A_dn[0]
    bool fastA = true;
    #pragma unroll
    for (int n = 1; n < NS; n++)
        fastA = fastA &&
            (fabsf(A_dn[n] - (float)(n+1)*A_dn[0]) <= 1e-3f*fabsf(A_dn[n]) + 1e-6f);

    float AcA[NS], BcA[NS];
    if (fastA) {
        float e1[8], ep[8];
        #pragma unroll
        for (int j = 0; j < 8; j++) { e1[j] = __expf(A_dn[0]*d8[j]); ep[j] = e1[j]; }
        #pragma unroll
        for (int n = 0; n < NS; n++) {
            half8 bv = *(const half8*)&P[BS_ + n*136 + 8*s];
            float Bc = 0.0f;
            #pragma unroll
            for (int j = 0; j < 8; j++)
                Bc = fmaf(ep[j], Bc, du8[j]*(float)bv[j]);
            BcA[n] = Bc;
            AcA[n] = __expf(A_dn[n]*loc8);
            if (n < NS-1) {
                #pragma unroll
                for (int j = 0; j < 8; j++) ep[j] *= e1[j];
            }
        }
    } else {
        #pragma unroll
        for (int n = 0; n < NS; n++) {
            half8 bv = *(const half8*)&P[BS_ + n*136 + 8*s];
            float Bc = 0.0f;
            #pragma unroll
            for (int j = 0; j < 8; j++) {
                float a = __expf(A_dn[n]*d8[j]);
                Bc = fmaf(a, Bc, du8[j]*(float)bv[j]);
            }
            BcA[n] = Bc;
            AcA[n] = __expf(A_dn[n]*loc8);
        }
    }
    #pragma unroll
    for (int n = 0; n < NS; n++) { OPSCAN16(AcA[n], BcA[n]); }
    if (s == 15) {
        const size_t o0 = ((size_t)bd*NS)*NCB + c;
        #pragma unroll
        for (int n = 0; n < NS; n++) {
            ap_ws[o0 + (size_t)n*NCB] = AcA[n];
            rs_ws[o0 + (size_t)n*NCB] = BcA[n];
        }
    }
}

// =============== kC3: inter-chunk scan + in-place active fixup ===========
// One wave per (b,d). Phase 1: prefix scans (sc + composed rs) kept in
// LDS/registers. Phase 2: for active chunks (c >= cmin), 4 chunks in
// parallel (16-lane groups), recompute the damp-gated scan and overwrite
// out. kD is gone.
__global__ __launch_bounds__(64) void kC3(
    const float* __restrict__ ap_ws, const float* __restrict__ rs_ws,
    const float* __restrict__ sc_ws, const float* __restrict__ A_log,
    const float* __restrict__ D_param,
    const h16* __restrict__ dh, const h16* __restrict__ uh,
    const h16* __restrict__ Bh, const h16* __restrict__ Ch,
    float* __restrict__ out)
{
    __shared__ float sc_l[NCB];        // exclusive delta-prefix per chunk
    __shared__ float rs_l[NS][NCB];    // composed incoming state per chunk
    const int bd   = blockIdx.x;
    const int lane = threadIdx.x;
    const int b    = bd / DI;
    const int d    = bd - b*DI;

    // ---------- Phase 1a: sc prefix scan ----------
    const size_t sb = (size_t)bd*NCB + lane*4;
    float4 sv = *(const float4*)(sc_ws + sb);
    float l1 = sv.x, l2 = l1 + sv.y, l3 = l2 + sv.z, l4 = l3 + sv.w;
    float inc = l4;
    #pragma unroll
    for (int off = 1; off < 64; off <<= 1) {
        float t = __shfl_up(inc, off);
        if (lane >= off) inc += t;
    }
    float ex = __shfl_up(inc, 1);
    if (lane == 0) ex = 0.0f;
    *(float4*)(&sc_l[lane*4]) = make_float4(ex, ex + l1, ex + l2, ex + l3);
    const float Tot = __shfl(inc, 63);

    // ---------- Phase 1b: first active chunk (gate monotonic in c) ------
    float mnlog = A_log[d*NS];
    #pragma unroll
    for (int n = 1; n < NS; n++) mnlog = fminf(mnlog, A_log[d*NS + n]);
    const float Amax = -__expf(mnlog);
    int cand = NCB;
    if (fmaf(Amax, Tot - (ex + l4), 40.0f) > 0.0f) cand = lane*4 + 3;
    if (fmaf(Amax, Tot - (ex + l3), 40.0f) > 0.0f) cand = lane*4 + 2;
    if (fmaf(Amax, Tot - (ex + l2), 40.0f) > 0.0f) cand = lane*4 + 1;
    if (fmaf(Amax, Tot - (ex + l1), 40.0f) > 0.0f) cand = lane*4 + 0;
    #pragma unroll
    for (int off = 32; off > 0; off >>= 1)
        cand = min(cand, __shfl_xor(cand, off));

    // ---------- Phase 1c: composed incoming-state scan -> LDS -----------
    #pragma unroll 2
    for (int n = 0; n < NS; n++) {
        const size_t base = ((size_t)bd*NS + n)*NCB + lane*4;
        float4 av = *(const float4*)(ap_ws + base);
        float4 rv = *(const float4*)(rs_ws + base);
        float Ac = av.x, Bc = rv.x;
        Bc = fmaf(av.y, Bc, rv.y); Ac *= av.y;
        Bc = fmaf(av.z, Bc, rv.z); Ac *= av.z;
        Bc = fmaf(av.w, Bc, rv.w); Ac *= av.w;
        #pragma unroll
        for (int off = 1; off < 64; off <<= 1) {
            float aP = __shfl_up(Ac, off);
            float bP = __shfl_up(Bc, off);
            if (lane >= off) { Bc = fmaf(Ac, bP, Bc); Ac *= aP; }
        }
        float pB = __shfl_up(Bc, 1);
        if (lane == 0) pB = 0.0f;
        float r  = pB;
        float o0 = r; r = fmaf(av.x, r, rv.x);
        float o1 = r; r = fmaf(av.y, r, rv.y);
        float o2 = r; r = fmaf(av.z, r, rv.z);
        *(float4*)(&rs_l[n][lane*4]) = make_float4(o0, o1, o2, r);
    }
    __syncthreads();

    if (cand >= NCB) return;        // no active chunks: k1's default y stands
    const int cmin = cand;

    // ---------- Phase 2: active fixup, 4 chunks per round ----------------
    float A_dn[NS];
    #pragma unroll
    for (int n = 0; n < NS; n++) A_dn[n] = -__expf(A_log[d*NS + n]);
    bool fastA = true;
    #pragma unroll
    for (int n = 1; n < NS; n++)
        fastA = fastA &&
            (fabsf(A_dn[n] - (float)(n+1)*A_dn[0]) <= 1e-3f*fabsf(A_dn[n]) + 1e-6f);
    const float Dd = D_param[d];
    const int g = lane >> 4;
    const int s = lane & 15;

    for (int cb = cmin; cb < NCB; cb += 4) {
        const int c = cb + g;
        if (c < NCB) {
            const size_t t0 = (size_t)c*TBLK + s*8;
            // bulk loads
            half8 uvv = *(const half8*)(uh + (size_t)bd*L_ + t0);
            half8 dvv = *(const half8*)(dh + (size_t)bd*L_ + t0);
            half8 bvA[NS], cvA[NS];
            #pragma unroll
            for (int n = 0; n < NS; n++) {
                bvA[n] = *(const half8*)(Bh + (size_t)(b*NS + n)*L_ + t0);
                cvA[n] = *(const half8*)(Ch + (size_t)(b*NS + n)*L_ + t0);
            }
            float rin[NS];
            #pragma unroll
            for (int n = 0; n < NS; n++) rin[n] = rs_l[n][c];
            const float scc = sc_l[c];

            float u8[8], d8[8], du8[8];
            #pragma unroll
            for (int j = 0; j < 8; j++) {
                u8[j] = (float)uvv[j];
                d8[j] = (float)dvv[j];
                du8[j] = d8[j]*u8[j];
            }
            float lp[8];
            { float run = 0.0f;
              #pragma unroll
              for (int j = 0; j < 8; j++) { run += d8[j]; lp[j] = run; } }
            float inc2 = lp[7];
            SUMSCAN16(inc2);
            float ex2 = dppf<ROW_SHR1>(0.0f, inc2);
            const float basep = scc + ex2;

            float yacc[8];
            #pragma unroll
            for (int j = 0; j < 8; j++) yacc[j] = 0.0f;

            if (fastA) {
                float e1[8], ep[8];
                #pragma unroll
                for (int j = 0; j < 8; j++) { e1[j] = __expf(A_dn[0]*d8[j]); ep[j] = e1[j]; }
                #pragma unroll
                for (int n = 0; n < NS; n++) {
                    float b8[8];
                    #pragma unroll
                    for (int j = 0; j < 8; j++) b8[j] = du8[j]*(float)bvA[n][j];
                    float Bc = 0.0f;
                    #pragma unroll
                    for (int j = 0; j < 8; j++) Bc = fmaf(ep[j], Bc, b8[j]);
                    float Ac = __expf(A_dn[n]*lp[7]);
                    OPSCAN16(Ac, Bc);
                    float pA = dppf<ROW_SHR1>(1.0f, Ac);
                    float pB = dppf<ROW_SHR1>(0.0f, Bc);
                    float r  = fmaf(pA, rin[n], pB);

                    float G[8];
                    G[7] = __expf(A_dn[n]*(Tot - (basep + lp[7])));
                    #pragma unroll
                    for (int j = 6; j >= 0; j--) G[j] = G[j+1]*ep[j+1];
                    #pragma unroll
                    for (int j = 0; j < 8; j++) {
                        r = fmaf(ep[j], r, b8[j]);
                        float damp = G[j] * __builtin_amdgcn_rcpf(G[j] + 1e-12f);
                        yacc[j] = fmaf((float)cvA[n][j]*damp, r, yacc[j]);
                    }
                    if (n < NS-1) {
                        #pragma unroll
                        for (int j = 0; j < 8; j++) ep[j] *= e1[j];
                    }
                }
            } else {
                #pragma unroll 2
                for (int n = 0; n < NS; n++) {
                    float a8[8], b8[8];
                    #pragma unroll
                    for (int j = 0; j < 8; j++) {
                        a8[j] = __expf(A_dn[n]*d8[j]);
                        b8[j] = du8[j]*(float)bvA[n][j];
                    }
                    float Bc = 0.0f;
                    #pragma unroll
                    for (int j = 0; j < 8; j++) Bc = fmaf(a8[j], Bc, b8[j]);
                    float Ac = __expf(A_dn[n]*lp[7]);
                    OPSCAN16(Ac, Bc);
                    float pA = dppf<ROW_SHR1>(1.0f, Ac);
                    float pB = dppf<ROW_SHR1>(0.0f, Bc);
                    float r  = fmaf(pA, rin[n], pB);

                    float G[8];
                    G[7] = __expf(A_dn[n]*(Tot - (basep + lp[7])));
                    #pragma unroll
                    for (int j = 6; j >= 0; j--) G[j] = G[j+1]*a8[j+1];
                    #pragma unroll
                    for (int j = 0; j < 8; j++) {
                        r = fmaf(a8[j], r, b8[j]);
                        float damp = G[j] * __builtin_amdgcn_rcpf(G[j] + 1e-12f);
                        yacc[j] = fmaf((float)cvA[n][j]*damp, r, yacc[j]);
                    }
                }
            }

            // overwrite k1's default y for this (chunk, d)
            float* ob = out + ((size_t)b*L_ + t0)*DI + d;
            #pragma unroll
            for (int j = 0; j < 8; j++)
                ob[j*DI] = fmaf(u8[j], Dd, yacc[j]);
        }
    }
}

extern "C" void kernel_launch(void* const* d_in, const int* in_sizes, int n_in,
                              void* d_out, int out_size, void* d_ws, size_t ws_size,
                              hipStream_t stream) {
    const float* x      = (const float*)d_in[0];
    const float* w_in   = (const float*)d_in[1];
    const float* b_in   = (const float*)d_in[2];
    const float* conv_k = (const float*)d_in[3];
    const float* conv_b = (const float*)d_in[4];
    const float* w_x    = (const float*)d_in[5];
    const float* b_x    = (const float*)d_in[6];
    const float* w_dt   = (const float*)d_in[7];
    const float* b_dt   = (const float*)d_in[8];
    const float* A_log  = (const float*)d_in[9];
    const float* D_par  = (const float*)d_in[10];
    float* out = (float*)d_out;
    float* ws  = (float*)d_ws;

    float* ap_ws = ws + OFF_AP;
    float* rs_ws = ws + OFF_RS;
    float* sc_ws = ws + OFF_SC;
    h16*   hbase = (h16*)(ws + OFF_H16);
    h16* dh  = hbase + HD;
    h16* uh  = hbase + HU;
    h16* Bh  = hbase + HB;
    h16* Ch  = hbase + HC;

    k1<<<dim3(NCB, B_), 320, 0, stream>>>(x, w_in, b_in, conv_k, conv_b,
                                          w_x, b_x, w_dt, b_dt, A_log, D_par,
                                          dh, uh, Bh, Ch,
                                          ap_ws, rs_ws, sc_ws, out);
    kC3<<<B_*DI, 64, 0, stream>>>(ap_ws, rs_ws, sc_ws, A_log, D_par,
                                  dh, uh, Bh, Ch, out);
}